// Round 5
// baseline (62.039 us; speedup 1.0000x reference)
//
#include <hip/hip_runtime.h>

// y = sigmoid(x)*h + (1-sigmoid(x))*tanh(x)
// Memory-bound elementwise. rcp intrinsics, unroll-16 MLP probe, NT stores,
// exact-fit specialization (no per-iteration bounds checks).

#define UNROLL 16

typedef float f32x4 __attribute__((ext_vector_type(4)));

__device__ __forceinline__ float mamba_elem(float xx, float hh) {
    // clamp so exp(-2x) can't overflow; sigmoid/tanh saturated past +-15
    xx = fminf(fmaxf(xx, -15.0f), 15.0f);
    float e  = __expf(-xx);                          // exp(-x)
    float e2 = e * e;                                // exp(-2x)
    float g  = __builtin_amdgcn_rcpf(1.0f + e);      // sigmoid(x)
    float r2 = __builtin_amdgcn_rcpf(1.0f + e2);
    float t  = __builtin_fmaf(2.0f, r2, -1.0f);      // tanh(x) = 2/(1+e2)-1
    float omg = e * g;                               // 1 - g
    return __builtin_fmaf(g, hh, omg * t);
}

template <bool EXACT>
__global__ __launch_bounds__(256) void pseudo_mamba_kernel(
    const f32x4* __restrict__ x4,
    const f32x4* __restrict__ h4,
    f32x4* __restrict__ y4,
    int n4)
{
    int base = blockIdx.x * (256 * UNROLL) + threadIdx.x;

    f32x4 xv[UNROLL], hv[UNROLL];
#pragma unroll
    for (int u = 0; u < UNROLL; ++u) {
        int i = base + u * 256;
        if (EXACT || i < n4) { xv[u] = x4[i]; hv[u] = h4[i]; }
    }
#pragma unroll
    for (int u = 0; u < UNROLL; ++u) {
        int i = base + u * 256;
        if (!EXACT && i >= n4) continue;
        f32x4 yv;
        yv.x = mamba_elem(xv[u].x, hv[u].x);
        yv.y = mamba_elem(xv[u].y, hv[u].y);
        yv.z = mamba_elem(xv[u].z, hv[u].z);
        yv.w = mamba_elem(xv[u].w, hv[u].w);
        __builtin_nontemporal_store(yv, &y4[i]);
    }
}

extern "C" void kernel_launch(void* const* d_in, const int* in_sizes, int n_in,
                              void* d_out, int out_size, void* d_ws, size_t ws_size,
                              hipStream_t stream) {
    const f32x4* x4 = reinterpret_cast<const f32x4*>(d_in[0]);
    const f32x4* h4 = reinterpret_cast<const f32x4*>(d_in[1]);
    f32x4* y4 = reinterpret_cast<f32x4*>(d_out);
    int n = in_sizes[0];                 // 8192*4096
    int n4 = n >> 2;                     // float4 count
    int per_block = 256 * UNROLL;        // 4096
    int grid = (n4 + per_block - 1) / per_block;   // 2048, exact fit
    if (n4 % per_block == 0) {
        pseudo_mamba_kernel<true><<<grid, 256, 0, stream>>>(x4, h4, y4, n4);
    } else {
        pseudo_mamba_kernel<false><<<grid, 256, 0, stream>>>(x4, h4, y4, n4);
    }
}